// Round 1
// baseline (1947.628 us; speedup 1.0000x reference)
//
#include <hip/hip_runtime.h>

// Problem constants
#define B_   256
#define T_   512
#define E_   200
#define H_   100
#define H3_  300
#define NC_  5

__device__ __forceinline__ void fma4(float4& acc, float a, const float4& w) {
    acc.x = fmaf(a, w.x, acc.x);
    acc.y = fmaf(a, w.y, acc.y);
    acc.z = fmaf(a, w.z, acc.z);
    acc.w = fmaf(a, w.w, acc.w);
}

// ---------------------------------------------------------------------------
// T0: pack weights: W_ihT[k][j] = W_ih[j][k]  (200x300)
//     wcat[k][j]: j<100 -> W_ti[j][k]; j==100 -> W_lgr[0][k]; else 0  (100x104)
// ---------------------------------------------------------------------------
__global__ void k_pack(const float* __restrict__ W_ih, const float* __restrict__ W_ti,
                       const float* __restrict__ W_lgr,
                       float* __restrict__ wT, float* __restrict__ wcat) {
    int idx = blockIdx.x * 256 + threadIdx.x;
    if (idx < E_ * H3_) {
        int k = idx / H3_, j = idx - k * H3_;
        wT[idx] = W_ih[j * E_ + k];
    }
    int i2 = idx - E_ * H3_;
    if (i2 >= 0 && i2 < H_ * 104) {
        int k = i2 / 104, j = i2 - k * 104;
        float v = 0.0f;
        if (j < H_) v = W_ti[j * H_ + k];
        else if (j == H_) v = W_lgr[k];
        wcat[i2] = v;
    }
}

// ---------------------------------------------------------------------------
// A: xp[row][j] = scale(row) * dot(emb[txt[row]], W_ih[j]) + b_ih[j]
// 32 rows/block, 320 threads: c = tid%80 (75 active, 4 cols each), g = tid/80 (8 rows)
// ---------------------------------------------------------------------------
__global__ __launch_bounds__(320) void k_embgemm(
        const int* __restrict__ txt, const float* __restrict__ emb,
        const float* __restrict__ wT, const float* __restrict__ b_ih,
        float* __restrict__ xp) {
    __shared__ __align__(16) float A_lds[E_ * 36];   // [k][r], stride 36 (28.8 KB)
    __shared__ __align__(16) float W_lds[32 * 320];  // [kk][j], stride 320 (40 KB)
    __shared__ float scale_lds[32];

    int tid = threadIdx.x;
    int base = blockIdx.x * 32;

    // stage A (raw emb rows), coalesced on k
    for (int idx = tid; idx < 32 * E_; idx += 320) {
        int r = idx / E_, k = idx - r * E_;
        int row = txt[base + r];
        A_lds[k * 36 + r] = emb[(size_t)row * E_ + k];
    }
    __syncthreads();

    // per-row norm -> scale
    if (tid < 32) {
        float ss = 0.0f;
        for (int k = 0; k < E_; ++k) { float v = A_lds[k * 36 + tid]; ss = fmaf(v, v, ss); }
        float n = sqrtf(ss);
        scale_lds[tid] = (n > 1.0f) ? (1.0f / (n + 1e-7f)) : 1.0f;
    }

    int c = tid % 80, g = tid / 80;
    float4 acc[8];
#pragma unroll
    for (int i = 0; i < 8; ++i) acc[i] = make_float4(0.f, 0.f, 0.f, 0.f);

    for (int kc = 0; kc < E_; kc += 32) {
        int KC = min(32, E_ - kc);
        __syncthreads();
        for (int idx = tid; idx < KC * H3_; idx += 320) {
            int kk = idx / H3_, j = idx - kk * H3_;
            W_lds[kk * 320 + j] = wT[(kc + kk) * H3_ + j];
        }
        __syncthreads();
        if (c < 75) {
            for (int kk = 0; kk < KC; ++kk) {
                int k = kc + kk;
                float4 wv = *(const float4*)&W_lds[kk * 320 + c * 4];
                float4 a0 = *(const float4*)&A_lds[k * 36 + g * 8];
                float4 a1 = *(const float4*)&A_lds[k * 36 + g * 8 + 4];
                fma4(acc[0], a0.x, wv); fma4(acc[1], a0.y, wv);
                fma4(acc[2], a0.z, wv); fma4(acc[3], a0.w, wv);
                fma4(acc[4], a1.x, wv); fma4(acc[5], a1.y, wv);
                fma4(acc[6], a1.z, wv); fma4(acc[7], a1.w, wv);
            }
        }
    }

    if (c < 75) {
        float4 bv = *(const float4*)&b_ih[c * 4];
#pragma unroll
        for (int rr = 0; rr < 8; ++rr) {
            int r = g * 8 + rr;
            float s = scale_lds[r];
            float4 res;
            res.x = fmaf(acc[rr].x, s, bv.x);
            res.y = fmaf(acc[rr].y, s, bv.y);
            res.z = fmaf(acc[rr].z, s, bv.z);
            res.w = fmaf(acc[rr].w, s, bv.w);
            *(float4*)&xp[(size_t)(base + r) * H3_ + c * 4] = res;
        }
    }
}

// ---------------------------------------------------------------------------
// B: GRU scan. 1 block per batch row. 320 threads; thread j<300 holds W_hh row j
// in VGPRs; h in LDS (broadcast float4 reads). Threads j<100 do the gate math.
// ---------------------------------------------------------------------------
__global__ __launch_bounds__(320) void k_gru(
        const float* __restrict__ xp, const float* __restrict__ W_hh,
        const float* __restrict__ b_hh, float* __restrict__ rnn) {
    __shared__ __align__(16) float h_lds[104];
    __shared__ float hp_lds[H3_];

    int j = threadIdx.x;
    int b = blockIdx.x;

    float4 W4[25];
    float bh = 0.0f;
    if (j < H3_) {
        const float4* wr = (const float4*)(W_hh + (size_t)j * H_);
#pragma unroll
        for (int kk = 0; kk < 25; ++kk) W4[kk] = wr[kk];
        bh = b_hh[j];
    }
    if (j < 104) h_lds[j] = 0.0f;

    const float* xpb = xp + (size_t)b * T_ * H3_;
    float xr = 0.f, xz = 0.f, xn = 0.f;
    if (j < H_) { xr = xpb[j]; xz = xpb[H_ + j]; xn = xpb[2 * H_ + j]; }
    __syncthreads();

    for (int t = 0; t < T_; ++t) {
        float acc0 = bh, acc1 = 0.f, acc2 = 0.f, acc3 = 0.f;
        if (j < H3_) {
#pragma unroll
            for (int kk = 0; kk < 25; ++kk) {
                float4 hv = *(const float4*)&h_lds[kk * 4];
                acc0 = fmaf(W4[kk].x, hv.x, acc0);
                acc1 = fmaf(W4[kk].y, hv.y, acc1);
                acc2 = fmaf(W4[kk].z, hv.z, acc2);
                acc3 = fmaf(W4[kk].w, hv.w, acc3);
            }
            hp_lds[j] = (acc0 + acc1) + (acc2 + acc3);
        }
        // prefetch next step's x
        float nxr = 0.f, nxz = 0.f, nxn = 0.f;
        if (j < H_ && t + 1 < T_) {
            const float* xq = xpb + (size_t)(t + 1) * H3_;
            nxr = xq[j]; nxz = xq[H_ + j]; nxn = xq[2 * H_ + j];
        }
        __syncthreads();
        if (j < H_) {
            float hr = hp_lds[j], hz = hp_lds[H_ + j], hn = hp_lds[2 * H_ + j];
            float hold = h_lds[j];
            float r = 1.0f / (1.0f + expf(-(xr + hr)));
            float z = 1.0f / (1.0f + expf(-(xz + hz)));
            float ng = tanhf(xn + r * hn);
            float hnew = (1.0f - z) * ng + z * hold;
            h_lds[j] = hnew;
            rnn[((size_t)b * T_ + t) * H_ + j] = hnew;
            xr = nxr; xz = nxz; xn = nxn;
        }
        __syncthreads();
    }
}

// ---------------------------------------------------------------------------
// C: ti = rnn @ W_ti.T + b_ti ; lgr = rnn @ W_lgr[:, :H].T ; z = relu(att*mask)
// 64 rows/block, 256 threads: c = tid%32 (26 active, 4 cols), g = tid/32 (8 rows)
// ---------------------------------------------------------------------------
__global__ __launch_bounds__(256) void k_post(
        const float* __restrict__ rnn, const float* __restrict__ wcat,
        const float* __restrict__ b_ti, const int* __restrict__ lens,
        float* __restrict__ ti, float* __restrict__ lgr, float* __restrict__ zr) {
    __shared__ __align__(16) float A_lds[H_ * 72];   // [k][r], stride 72 (28.8 KB)
    __shared__ __align__(16) float W_lds[H_ * 112];  // [k][j], stride 112 (44.8 KB)

    int tid = threadIdx.x;
    int base = blockIdx.x * 64;

    for (int idx = tid; idx < 64 * H_; idx += 256) {
        int r = idx / H_, k = idx - r * H_;
        A_lds[k * 72 + r] = rnn[(size_t)(base + r) * H_ + k];
    }
    for (int idx = tid; idx < H_ * 104; idx += 256) {
        int k = idx / 104, jj = idx - k * 104;
        W_lds[k * 112 + jj] = wcat[idx];
    }
    __syncthreads();

    if (tid < 64) {
        float ss = 0.f, sm = 0.f;
        for (int k = 0; k < H_; ++k) {
            float v = A_lds[k * 72 + tid];
            ss = fmaf(v, v, ss); sm += v;
        }
        int row = base + tid;
        int bb = row >> 9, tt = row & 511;
        float att = sm / (fmaxf(sqrtf(ss), 1e-12f) * 1000.0f);  // / (norm * sqrt(H) * H)
        zr[row] = (tt < lens[bb]) ? fmaxf(att, 0.0f) : 0.0f;
    }

    int c = tid % 32, g = tid / 32;
    float4 acc[8];
#pragma unroll
    for (int i = 0; i < 8; ++i) acc[i] = make_float4(0.f, 0.f, 0.f, 0.f);

    if (c < 26) {
        for (int k = 0; k < H_; ++k) {
            float4 wv = *(const float4*)&W_lds[k * 112 + c * 4];
            float4 a0 = *(const float4*)&A_lds[k * 72 + g * 8];
            float4 a1 = *(const float4*)&A_lds[k * 72 + g * 8 + 4];
            fma4(acc[0], a0.x, wv); fma4(acc[1], a0.y, wv);
            fma4(acc[2], a0.z, wv); fma4(acc[3], a0.w, wv);
            fma4(acc[4], a1.x, wv); fma4(acc[5], a1.y, wv);
            fma4(acc[6], a1.z, wv); fma4(acc[7], a1.w, wv);
        }
    }

    if (c < 25) {
        float4 bv = *(const float4*)&b_ti[c * 4];
#pragma unroll
        for (int rr = 0; rr < 8; ++rr) {
            int row = base + g * 8 + rr;
            float4 res;
            res.x = acc[rr].x + bv.x; res.y = acc[rr].y + bv.y;
            res.z = acc[rr].z + bv.z; res.w = acc[rr].w + bv.w;
            *(float4*)&ti[(size_t)row * H_ + c * 4] = res;
        }
    } else if (c == 25) {
#pragma unroll
        for (int rr = 0; rr < 8; ++rr) {
            int row = base + g * 8 + rr;
            lgr[row] = acc[rr].x;  // j == 100 column
        }
    }
}

// ---------------------------------------------------------------------------
// D: rec scan + final GEMV. 1 block per batch row, 128 threads (2 waves).
// Thread j<100 holds W_ts row j in VGPRs; state in LDS; scalar gate dot via
// wave shuffle reduce + LDS cross-wave combine.
// ---------------------------------------------------------------------------
__global__ __launch_bounds__(128) void k_rec(
        const float* __restrict__ ti, const float* __restrict__ lgr,
        const float* __restrict__ zr,
        const float* __restrict__ W_ts, const float* __restrict__ b_ts,
        const float* __restrict__ W_lgr, const float* __restrict__ b_lgr,
        const float* __restrict__ W_out, const float* __restrict__ b_out,
        float* __restrict__ out) {
    __shared__ __align__(16) float s_lds[104];
    __shared__ float red[2];

    int j = threadIdx.x;
    int b = blockIdx.x;

    float4 Wt4[25];
    float wls = 0.f, bts = 0.f;
    if (j < H_) {
        const float4* wr = (const float4*)(W_ts + (size_t)j * H_);
#pragma unroll
        for (int kk = 0; kk < 25; ++kk) Wt4[kk] = wr[kk];
        wls = W_lgr[H_ + j];
        bts = b_ts[j];
    }
    float blg = b_lgr[0];
    if (j < 104) s_lds[j] = 0.0f;

    size_t rb = (size_t)b * T_;
    float tiv = 0.f, zt = 0.f, lt = 0.f;
    if (j < H_) tiv = ti[rb * H_ + j];
    zt = zr[rb]; lt = lgr[rb];
    __syncthreads();

    for (int t = 0; t < T_; ++t) {
        float a0 = 0.f, a1 = 0.f, a2 = 0.f, a3 = 0.f;
        float sj = 0.f, part = 0.f;
        if (j < H_) {
#pragma unroll
            for (int kk = 0; kk < 25; ++kk) {
                float4 sv4 = *(const float4*)&s_lds[kk * 4];
                a0 = fmaf(Wt4[kk].x, sv4.x, a0);
                a1 = fmaf(Wt4[kk].y, sv4.y, a1);
                a2 = fmaf(Wt4[kk].z, sv4.z, a2);
                a3 = fmaf(Wt4[kk].w, sv4.w, a3);
            }
            sj = s_lds[j];
            part = sj * wls;
        }
        // prefetch next step's inputs
        float ntiv = 0.f, nzt = 0.f, nlt = 0.f;
        if (t + 1 < T_) {
            if (j < H_) ntiv = ti[(rb + t + 1) * H_ + j];
            nzt = zr[rb + t + 1]; nlt = lgr[rb + t + 1];
        }
        // wave reduce the gate dot partial
#pragma unroll
        for (int off = 1; off < 64; off <<= 1) part += __shfl_xor(part, off, 64);
        if ((j & 63) == 0) red[j >> 6] = part;
        __syncthreads();
        float dot = red[0] + red[1];
        float gate = 1.0f / (1.0f + expf(-(lt + dot + blg)));
        if (j < H_) {
            float sv = (a0 + a1) + (a2 + a3);
            float ns = tanhf(tiv + gate * sv + bts);
            float snew = (1.0f - zt) * sj + zt * ns;
            s_lds[j] = snew;
        }
        tiv = ntiv; zt = nzt; lt = nlt;
        __syncthreads();
    }

    if (j < NC_) {
        float o = b_out[j];
        for (int k = 0; k < H_; ++k) o = fmaf(s_lds[k], W_out[j * H_ + k], o);
        out[b * NC_ + j] = o;
    }
}

// ---------------------------------------------------------------------------
extern "C" void kernel_launch(void* const* d_in, const int* in_sizes, int n_in,
                              void* d_out, int out_size, void* d_ws, size_t ws_size,
                              hipStream_t stream) {
    const int*   txt   = (const int*)d_in[0];
    const int*   lens  = (const int*)d_in[1];
    const float* emb   = (const float*)d_in[2];
    const float* W_ih  = (const float*)d_in[3];
    const float* W_hh  = (const float*)d_in[4];
    const float* b_ih  = (const float*)d_in[5];
    const float* b_hh  = (const float*)d_in[6];
    const float* W_lgr = (const float*)d_in[7];
    const float* b_lgr = (const float*)d_in[8];
    const float* W_ts  = (const float*)d_in[9];
    const float* b_ts  = (const float*)d_in[10];
    const float* W_ti  = (const float*)d_in[11];
    const float* b_ti  = (const float*)d_in[12];
    const float* W_out = (const float*)d_in[13];
    const float* b_out = (const float*)d_in[14];

    float* ws   = (float*)d_ws;
    float* xp   = ws;                    // 39,321,600 floats (157 MB)
    float* rnn  = xp + 39321600;         // 13,107,200 floats (52 MB)
    float* lgrv = rnn + 13107200;        // 131,072
    float* zrv  = lgrv + 131072;         // 131,072
    float* wT   = zrv + 131072;          // 60,000
    float* wcat = wT + 60000;            // 10,400
    float* ti   = xp;                    // reuse xp region after GRU

    float* out = (float*)d_out;

    k_pack<<<276, 256, 0, stream>>>(W_ih, W_ti, W_lgr, wT, wcat);
    k_embgemm<<<4096, 320, 0, stream>>>(txt, emb, wT, b_ih, xp);
    k_gru<<<256, 320, 0, stream>>>(xp, W_hh, b_hh, rnn);
    k_post<<<2048, 256, 0, stream>>>(rnn, wcat, b_ti, lens, ti, lgrv, zrv);
    k_rec<<<256, 128, 0, stream>>>(ti, lgrv, zrv, W_ts, b_ts, W_lgr, b_lgr,
                                   W_out, b_out, out);
}